// Round 5
// baseline (1568.292 us; speedup 1.0000x reference)
//
#include <hip/hip_runtime.h>
#include <hip/hip_bf16.h>
#include <cmath>

#define N_TOK 16384
#define D_DIM 2048
#define H_DIM 1024
#define E_DIM 64

typedef _Float16 half8 __attribute__((ext_vector_type(8)));
typedef float floatx4 __attribute__((ext_vector_type(4)));

// ---------------------------------------------------------------------------
// Transpose + split W1 [2048k][1024c] -> whT/wlT [1024c][2048k] f16.
// ---------------------------------------------------------------------------
__global__ __launch_bounds__(256) void splitT_w1_kernel(
    const float* __restrict__ W1, _Float16* __restrict__ whT,
    _Float16* __restrict__ wlT) {
  __shared__ float ls[64][65];
  const int k0 = blockIdx.x * 64;
  const int c0 = blockIdx.y * 64;
  const int t = threadIdx.x;
  const int tr = t >> 6;
  const int tc = t & 63;
#pragma unroll
  for (int i = 0; i < 16; i++) {
    int k = tr * 16 + i;
    ls[k][tc] = W1[(size_t)(k0 + k) * H_DIM + c0 + tc];
  }
  __syncthreads();
#pragma unroll
  for (int i = 0; i < 16; i++) {
    int c = tr * 16 + i;
    float v = ls[tc][c];
    _Float16 hv = (_Float16)v;
    _Float16 lv = (_Float16)(v - (float)hv);
    whT[(size_t)(c0 + c) * D_DIM + k0 + tc] = hv;
    wlT[(size_t)(c0 + c) * D_DIM + k0 + tc] = lv;
  }
}

// ---------------------------------------------------------------------------
// GEMM1 via f16 split MFMA, 256x256 tile, BK=32, 512 thr (8 waves 2Mx4N).
// A (x fp32): reg-staged -> split hi/lo -> swizzled LDS (64KB dbuf total
// -> 2 blocks/CU, barrier stalls overlap across blocks).
// B (whT/wlT, [col][k] f16): fragments loaded DIRECTLY global->reg with
// depth-1 ping-pong prefetch; never touches LDS (L1/L2 serve reuse).
// ---------------------------------------------------------------------------
__global__ __launch_bounds__(512, 4) void gemm1_mfma_kernel(
    const float* __restrict__ x,
    const _Float16* __restrict__ whT, const _Float16* __restrict__ wlT,
    float* __restrict__ h) {
  __shared__ __align__(16) char smem[65536];  // 2 x (Ah 16KB | Al 16KB)

  const int t = threadIdx.x;
  const int wave = t >> 6;
  const int lane = t & 63;

  // XCD-aware swizzle: 256 wgs, 8 XCDs.
  const int bid = blockIdx.x;
  const int swz = (bid & 7) * 32 + (bid >> 3);
  const int by = swz >> 2, bx = swz & 3;
  const int row0 = by * 256, col0 = bx * 256;
  const int wr = wave >> 2, wc = wave & 3;  // 2 x 4 wave grid

  floatx4 acc[8][4];
#pragma unroll
  for (int m = 0; m < 8; m++)
#pragma unroll
    for (int n = 0; n < 4; n++) acc[m][n] = (floatx4){0.f, 0.f, 0.f, 0.f};

  // ---- A reg-staging mapping: unit u = (row, kslot) of 8 f32 ----
  int awaddr[2];
  size_t gaoff[2];
#pragma unroll
  for (int q = 0; q < 2; q++) {
    const int u = q * 512 + t;
    const int arow = u >> 2;
    const int aslot = u & 3;
    awaddr[q] = arow * 64 + ((aslot ^ ((arow >> 1) & 3)) << 4);
    gaoff[q] = (size_t)(row0 + arow) * D_DIM + aslot * 8;
  }

  const int kg = lane >> 4;
  const int fr = lane & 15;

  // A fragment ds_read byte addresses (within 16KB array), swizzle-matched.
  int aaddr[8];
#pragma unroll
  for (int m = 0; m < 8; m++) {
    const int r = wr * 128 + m * 16 + fr;
    aaddr[m] = r * 64 + ((kg ^ ((r >> 1) & 3)) << 4);
  }

  // B fragment global offsets (elements): col-major [col][k] layout.
  size_t bgoff[4];
#pragma unroll
  for (int n = 0; n < 4; n++) {
    const int c = col0 + wc * 64 + n * 16 + fr;
    bgoff[n] = (size_t)c * D_DIM + kg * 8;
  }

  float4 av[2][2];
  half8 b0h[4], b0l[4], b1h[4], b1l[4];

#define LOAD_A(kt)                                                             \
  do {                                                                         \
    const size_t kk = (size_t)(kt) * 32;                                       \
    av[0][0] = *(const float4*)(x + gaoff[0] + kk);                            \
    av[0][1] = *(const float4*)(x + gaoff[0] + kk + 4);                        \
    av[1][0] = *(const float4*)(x + gaoff[1] + kk);                            \
    av[1][1] = *(const float4*)(x + gaoff[1] + kk + 4);                        \
  } while (0)

#define WRITE_A(buf)                                                           \
  do {                                                                         \
    char* lb = smem + (buf) * 32768;                                           \
    _Pragma("unroll") for (int q = 0; q < 2; q++) {                            \
      float vs[8] = {av[q][0].x, av[q][0].y, av[q][0].z, av[q][0].w,           \
                     av[q][1].x, av[q][1].y, av[q][1].z, av[q][1].w};          \
      half8 hh, ll;                                                            \
      _Pragma("unroll") for (int j = 0; j < 8; j++) {                          \
        _Float16 hv = (_Float16)vs[j];                                         \
        hh[j] = hv;                                                            \
        ll[j] = (_Float16)(vs[j] - (float)hv);                                 \
      }                                                                        \
      *(half8*)(lb + awaddr[q]) = hh;                                          \
      *(half8*)(lb + 16384 + awaddr[q]) = ll;                                  \
    }                                                                          \
  } while (0)

#define LOAD_B(BH, BL, kt)                                                     \
  do {                                                                         \
    const size_t kk = (size_t)(kt) * 32;                                       \
    _Pragma("unroll") for (int n = 0; n < 4; n++) {                            \
      BH[n] = *(const half8*)(whT + bgoff[n] + kk);                            \
      BL[n] = *(const half8*)(wlT + bgoff[n] + kk);                            \
    }                                                                          \
  } while (0)

#define BODY(kt, BH_CUR, BL_CUR, BH_NXT, BL_NXT)                               \
  do {                                                                         \
    if ((kt) < 63) {                                                           \
      LOAD_A((kt) + 1);                                                        \
      LOAD_B(BH_NXT, BL_NXT, (kt) + 1);                                        \
    }                                                                          \
    __builtin_amdgcn_sched_barrier(0);                                         \
    const char* pAh = smem + ((kt) & 1) * 32768;                               \
    const char* pAl = pAh + 16384;                                             \
    _Pragma("unroll") for (int m = 0; m < 8; m++) {                            \
      half8 ah = *(const half8*)(pAh + aaddr[m]);                              \
      half8 al = *(const half8*)(pAl + aaddr[m]);                              \
      __builtin_amdgcn_s_setprio(1);                                           \
      _Pragma("unroll") for (int n = 0; n < 4; n++) {                          \
        acc[m][n] = __builtin_amdgcn_mfma_f32_16x16x32_f16(ah, BH_CUR[n],      \
                                                           acc[m][n], 0, 0, 0);\
        acc[m][n] = __builtin_amdgcn_mfma_f32_16x16x32_f16(ah, BL_CUR[n],      \
                                                           acc[m][n], 0, 0, 0);\
        acc[m][n] = __builtin_amdgcn_mfma_f32_16x16x32_f16(al, BH_CUR[n],      \
                                                           acc[m][n], 0, 0, 0);\
      }                                                                        \
      __builtin_amdgcn_s_setprio(0);                                           \
    }                                                                          \
    if ((kt) < 63) WRITE_A(((kt) & 1) ^ 1);                                    \
    __syncthreads();                                                           \
  } while (0)

  // Prologue: tile 0 into buf0 + B set 0.
  LOAD_A(0);
  LOAD_B(b0h, b0l, 0);
  WRITE_A(0);
  __syncthreads();

#pragma unroll 1
  for (int kt2 = 0; kt2 < 32; ++kt2) {
    const int kt = kt2 * 2;
    BODY(kt, b0h, b0l, b1h, b1l);
    BODY(kt + 1, b1h, b1l, b0h, b0l);
  }
#undef LOAD_A
#undef WRITE_A
#undef LOAD_B
#undef BODY

  // Epilogue: C/D layout col=lane&15, row=(lane>>4)*4+j  [m89-verified]
  const int rj = (lane >> 4) * 4;
#pragma unroll
  for (int m = 0; m < 8; m++) {
    const int rbase = row0 + wr * 128 + m * 16 + rj;
#pragma unroll
    for (int n = 0; n < 4; n++) {
      const int c = col0 + wc * 64 + n * 16 + fr;
#pragma unroll
      for (int j = 0; j < 4; j++) {
        h[(size_t)(rbase + j) * H_DIM + c] = acc[m][n][j];
      }
    }
  }
}

// ---------------------------------------------------------------------------
// Kernel 2: per 8 tokens: +b1, LayerNorm, exact GELU, logits = g @ W2 + b2,
// softmax, top-2 (lower-index tie-break), renorm weights.
// ---------------------------------------------------------------------------
__device__ __forceinline__ float gelu_exact(float v) {
  return 0.5f * v * (1.0f + erff(v * 0.70710678118654752f));
}

__global__ __launch_bounds__(256) void router_kernel(
    const float* __restrict__ hbuf, const float* __restrict__ b1,
    const float* __restrict__ gamma, const float* __restrict__ beta,
    const float* __restrict__ W2, const float* __restrict__ b2,
    float* __restrict__ out) {
  __shared__ float g[8][H_DIM];
  __shared__ float w2s[128][E_DIM];
  __shared__ float lg[8][E_DIM];

  const int t = threadIdx.x;
  const int tok0 = blockIdx.x * 8;

  const int tk = t >> 5;
  const int l32 = t & 31;
  float vals[32];
  {
    const float* hr = hbuf + (size_t)(tok0 + tk) * H_DIM;
    float s = 0.f, s2 = 0.f;
#pragma unroll
    for (int q = 0; q < 8; q++) {
      const int j = q * 128 + l32 * 4;
      float4 v = *(const float4*)(hr + j);
      float4 bb = *(const float4*)(b1 + j);
      v.x += bb.x; v.y += bb.y; v.z += bb.z; v.w += bb.w;
      vals[q * 4 + 0] = v.x; vals[q * 4 + 1] = v.y;
      vals[q * 4 + 2] = v.z; vals[q * 4 + 3] = v.w;
      s += v.x + v.y + v.z + v.w;
      s2 += v.x * v.x + v.y * v.y + v.z * v.z + v.w * v.w;
    }
#pragma unroll
    for (int off = 16; off; off >>= 1) {
      s += __shfl_xor(s, off, 32);
      s2 += __shfl_xor(s2, off, 32);
    }
    const float mean = s * (1.f / 1024.f);
    const float var = s2 * (1.f / 1024.f) - mean * mean;
    const float rstd = rsqrtf(var + 1e-5f);
#pragma unroll
    for (int q = 0; q < 8; q++) {
      const int j = q * 128 + l32 * 4;
      float4 gm = *(const float4*)(gamma + j);
      float4 bt = *(const float4*)(beta + j);
      float4 o;
      o.x = gelu_exact((vals[q * 4 + 0] - mean) * rstd * gm.x + bt.x);
      o.y = gelu_exact((vals[q * 4 + 1] - mean) * rstd * gm.y + bt.y);
      o.z = gelu_exact((vals[q * 4 + 2] - mean) * rstd * gm.z + bt.z);
      o.w = gelu_exact((vals[q * 4 + 3] - mean) * rstd * gm.w + bt.w);
      *(float4*)&g[tk][j] = o;
    }
  }

  {
    float* lgf = &lg[0][0];
    lgf[t] = b2[t & 63];
    lgf[t + 256] = b2[t & 63];
  }

  const int seg = t >> 6;
  const int cell = t & 63;
  const int tp = cell >> 4;
  const int e0 = (cell & 15) * 4;

  float acc0[4] = {0.f, 0.f, 0.f, 0.f};
  float acc1[4] = {0.f, 0.f, 0.f, 0.f};

  for (int c = 0; c < 8; c++) {
    __syncthreads();
#pragma unroll
    for (int q = 0; q < 8; q++) {
      const int idx = q * 1024 + t * 4;
      *(float4*)(&w2s[0][0] + idx) = *(const float4*)(W2 + c * 8192 + idx);
    }
    __syncthreads();
#pragma unroll
    for (int q = 0; q < 8; q++) {
      const int i = seg * 32 + q * 4;
      float4 g0 = *(const float4*)&g[2 * tp][c * 128 + i];
      float4 g1 = *(const float4*)&g[2 * tp + 1][c * 128 + i];
      float4 w0 = *(const float4*)&w2s[i + 0][e0];
      float4 w1 = *(const float4*)&w2s[i + 1][e0];
      float4 w2v = *(const float4*)&w2s[i + 2][e0];
      float4 w3 = *(const float4*)&w2s[i + 3][e0];
      acc0[0] = fmaf(g0.x, w0.x, acc0[0]); acc0[1] = fmaf(g0.x, w0.y, acc0[1]);
      acc0[2] = fmaf(g0.x, w0.z, acc0[2]); acc0[3] = fmaf(g0.x, w0.w, acc0[3]);
      acc0[0] = fmaf(g0.y, w1.x, acc0[0]); acc0[1] = fmaf(g0.y, w1.y, acc0[1]);
      acc0[2] = fmaf(g0.y, w1.z, acc0[2]); acc0[3] = fmaf(g0.y, w1.w, acc0[3]);
      acc0[0] = fmaf(g0.z, w2v.x, acc0[0]); acc0[1] = fmaf(g0.z, w2v.y, acc0[1]);
      acc0[2] = fmaf(g0.z, w2v.z, acc0[2]); acc0[3] = fmaf(g0.z, w2v.w, acc0[3]);
      acc0[0] = fmaf(g0.w, w3.x, acc0[0]); acc0[1] = fmaf(g0.w, w3.y, acc0[1]);
      acc0[2] = fmaf(g0.w, w3.z, acc0[2]); acc0[3] = fmaf(g0.w, w3.w, acc0[3]);
      acc1[0] = fmaf(g1.x, w0.x, acc1[0]); acc1[1] = fmaf(g1.x, w0.y, acc1[1]);
      acc1[2] = fmaf(g1.x, w0.z, acc1[2]); acc1[3] = fmaf(g1.x, w0.w, acc1[3]);
      acc1[0] = fmaf(g1.y, w1.x, acc1[0]); acc1[1] = fmaf(g1.y, w1.y, acc1[1]);
      acc1[2] = fmaf(g1.y, w1.z, acc1[2]); acc1[3] = fmaf(g1.y, w1.w, acc1[3]);
      acc1[0] = fmaf(g1.z, w2v.x, acc1[0]); acc1[1] = fmaf(g1.z, w2v.y, acc1[1]);
      acc1[2] = fmaf(g1.z, w2v.z, acc1[2]); acc1[3] = fmaf(g1.z, w2v.w, acc1[3]);
      acc1[0] = fmaf(g1.w, w3.x, acc1[0]); acc1[1] = fmaf(g1.w, w3.y, acc1[1]);
      acc1[2] = fmaf(g1.w, w3.z, acc1[2]); acc1[3] = fmaf(g1.w, w3.w, acc1[3]);
    }
  }
#pragma unroll
  for (int j = 0; j < 4; j++) {
    atomicAdd(&lg[2 * tp][e0 + j], acc0[j]);
    atomicAdd(&lg[2 * tp + 1][e0 + j], acc1[j]);
  }
  __syncthreads();

  float* out_idx = out;
  float* out_w = out + 32768;
  float* out_logits = out + 65536;

  const int wv = t >> 6;
  const int lane = t & 63;
#pragma unroll
  for (int tt = 0; tt < 2; tt++) {
    const int tok = wv * 2 + tt;
    const int n = tok0 + tok;
    const float L = lg[tok][lane];
    float m = L;
#pragma unroll
    for (int off = 32; off; off >>= 1) m = fmaxf(m, __shfl_xor(m, off));
    const float ex = expf(L - m);
    float sum = ex;
#pragma unroll
    for (int off = 32; off; off >>= 1) sum += __shfl_xor(sum, off);
    const float p = ex / sum;

    float v1 = p; int i1 = lane;
#pragma unroll
    for (int off = 32; off; off >>= 1) {
      float ov = __shfl_xor(v1, off);
      int oi = __shfl_xor(i1, off);
      if (ov > v1 || (ov == v1 && oi < i1)) { v1 = ov; i1 = oi; }
    }
    float v2 = (lane == i1) ? -1.f : p; int i2 = lane;
#pragma unroll
    for (int off = 32; off; off >>= 1) {
      float ov = __shfl_xor(v2, off);
      int oi = __shfl_xor(i2, off);
      if (ov > v2 || (ov == v2 && oi < i2)) { v2 = ov; i2 = oi; }
    }

    out_logits[(size_t)n * 64 + lane] = L;
    if (lane == 0) {
      const float dn = v1 + v2 + 1e-9f;
      out_idx[n * 2 + 0] = (float)i1;
      out_idx[n * 2 + 1] = (float)i2;
      out_w[n * 2 + 0] = v1 / dn;
      out_w[n * 2 + 1] = v2 / dn;
    }
  }
}

extern "C" void kernel_launch(void* const* d_in, const int* in_sizes, int n_in,
                              void* d_out, int out_size, void* d_ws, size_t ws_size,
                              hipStream_t stream) {
  const float* x = (const float*)d_in[0];
  const float* W1 = (const float*)d_in[1];
  const float* b1 = (const float*)d_in[2];
  const float* gamma = (const float*)d_in[3];
  const float* beta = (const float*)d_in[4];
  const float* W2 = (const float*)d_in[5];
  const float* b2 = (const float*)d_in[6];
  float* out = (float*)d_out;

  char* ws = (char*)d_ws;
  _Float16* whT = (_Float16*)ws;                 // 4 MiB
  _Float16* wlT = (_Float16*)(ws + 4194304);     // 4 MiB
  float* hbuf = (float*)(ws + 8388608);          // 64 MiB (total 72 MiB)

  splitT_w1_kernel<<<dim3(D_DIM / 64, H_DIM / 64), 256, 0, stream>>>(W1, whT, wlT);

  gemm1_mfma_kernel<<<256, 512, 0, stream>>>(x, whT, wlT, hbuf);

  router_kernel<<<N_TOK / 8, 256, 0, stream>>>(hbuf, b1, gamma, beta, W2, b2, out);
}

// Round 6
// 320.660 us; speedup vs baseline: 4.8908x; 4.8908x over previous
//
#include <hip/hip_runtime.h>
#include <hip/hip_bf16.h>
#include <cmath>

#define N_TOK 16384
#define D_DIM 2048
#define H_DIM 1024
#define E_DIM 64

typedef _Float16 half8 __attribute__((ext_vector_type(8)));
typedef float f32x16 __attribute__((ext_vector_type(16)));

#define GLOAD_LDS(gp, lp)                                                      \
  __builtin_amdgcn_global_load_lds(                                            \
      (const __attribute__((address_space(1))) unsigned int*)(gp),             \
      (__attribute__((address_space(3))) unsigned int*)(lp), 16, 0, 0)

// ---------------------------------------------------------------------------
// Transpose + split W1 [2048k][1024c] -> whT/wlT [1024c][2048k] f16.
// ---------------------------------------------------------------------------
__global__ __launch_bounds__(256) void splitT_w1_kernel(
    const float* __restrict__ W1, _Float16* __restrict__ whT,
    _Float16* __restrict__ wlT) {
  __shared__ float ls[64][65];
  const int k0 = blockIdx.x * 64;
  const int c0 = blockIdx.y * 64;
  const int t = threadIdx.x;
  const int tr = t >> 6;
  const int tc = t & 63;
#pragma unroll
  for (int i = 0; i < 16; i++) {
    int k = tr * 16 + i;
    ls[k][tc] = W1[(size_t)(k0 + k) * H_DIM + c0 + tc];
  }
  __syncthreads();
#pragma unroll
  for (int i = 0; i < 16; i++) {
    int c = tr * 16 + i;
    float v = ls[tc][c];
    _Float16 hv = (_Float16)v;
    _Float16 lv = (_Float16)(v - (float)hv);
    whT[(size_t)(c0 + c) * D_DIM + k0 + tc] = hv;
    wlT[(size_t)(c0 + c) * D_DIM + k0 + tc] = lv;
  }
}

// ---------------------------------------------------------------------------
// GEMM1: h = x @ W1 via f16 hi/lo split, 32x32x16 MFMA, 256x256 tile, BK=16.
// 512 thr (8 waves 2Mx4N), 4-buffer LDS ring (4 x 32KB), prefetch depth 2,
// counted vmcnt(4) (T4) -- loads stay in flight across barriers.
// A (x fp32): reg-staged, split fused in-register, swizzled ds_write.
// B (whT/wlT pre-split f16): global_load_lds with swizzled source.
// Per tile: 2 phases {ds_read frags; barrier; lgkm0; 12 MFMA setprio}.
// ---------------------------------------------------------------------------
__global__ __launch_bounds__(512, 2) void gemm1_mfma_kernel(
    const float* __restrict__ x, const _Float16* __restrict__ whT,
    const _Float16* __restrict__ wlT, float* __restrict__ h) {
  extern __shared__ __align__(16) char smem[];  // 4 x 32KB: Ah|Al|Bh|Bl

  const int t = threadIdx.x;
  const int wave = t >> 6;
  const int lane = t & 63;
  const int l31 = lane & 31;
  const int kg = lane >> 5;

  const int bid = blockIdx.x;
  const int swz = (bid & 7) * 32 + (bid >> 3);  // XCD swizzle (256 = 8*32)
  const int by = swz >> 2, bx = swz & 3;
  const int row0 = by * 256, col0 = bx * 256;
  const int wr = wave >> 2, wc = wave & 3;  // 2x4 wave grid, wave tile 128x64

  f32x16 acc[4][2];
#pragma unroll
  for (int m = 0; m < 4; m++)
#pragma unroll
    for (int n = 0; n < 2; n++)
#pragma unroll
      for (int j = 0; j < 16; j++) acc[m][n][j] = 0.f;

  // ---- A reg-staging: thread owns (row ar, k-half akh) = 8 fp32 ----
  const int ar = t >> 1;
  const int akh = t & 1;
  const int as = akh ^ ((ar >> 2) & 1);      // swizzled 16B slot
  const int awAh = ar * 32 + as * 16;        // byte within Ah array
  const size_t ga = (size_t)(row0 + ar) * D_DIM + akh * 8;  // + T*16

  // ---- B gload_lds staging: dest linear, source slot pre-swizzled ----
  const size_t gb =
      (size_t)(col0 + (t >> 1)) * D_DIM + ((t & 1) ^ ((t >> 3) & 1)) * 8;
  const int bdst = wave * 1024;  // + buf*32768 + {16384,24576}

  // ---- fragment ds_read offsets (within 8KB array), swizzle-matched ----
  const int sfr = ((lane >> 5) ^ (lane >> 2)) & 1;
  int afr[4], bfr[2];
#pragma unroll
  for (int m = 0; m < 4; m++)
    afr[m] = (wr * 128 + m * 32 + l31) * 32 + sfr * 16;
#pragma unroll
  for (int n = 0; n < 2; n++)
    bfr[n] = (wc * 64 + n * 32 + l31) * 32 + sfr * 16;

  float4 av0, av1;  // in-flight A fp32 (tile T+2 during tile T)

#define LOAD_A(T)                                                              \
  do {                                                                         \
    const float* pa = x + ga + (size_t)(T) * 16;                               \
    av0 = *(const float4*)pa;                                                  \
    av1 = *(const float4*)(pa + 4);                                            \
  } while (0)

#define WRITE_A(B)                                                             \
  do {                                                                         \
    float vs[8] = {av0.x, av0.y, av0.z, av0.w, av1.x, av1.y, av1.z, av1.w};    \
    half8 hh, ll;                                                              \
    _Pragma("unroll") for (int j = 0; j < 8; j++) {                            \
      _Float16 hv = (_Float16)vs[j];                                           \
      hh[j] = hv;                                                              \
      ll[j] = (_Float16)(vs[j] - (float)hv);                                   \
    }                                                                          \
    char* wb = smem + (B) * 32768;                                             \
    *(half8*)(wb + awAh) = hh;                                                 \
    *(half8*)(wb + 8192 + awAh) = ll;                                          \
  } while (0)

#define GLD_B(T)                                                               \
  do {                                                                         \
    const size_t ko = gb + (size_t)(T) * 16;                                   \
    char* db = smem + ((T) & 3) * 32768;                                       \
    GLOAD_LDS(whT + ko, db + 16384 + bdst);                                    \
    GLOAD_LDS(wlT + ko, db + 24576 + bdst);                                    \
  } while (0)

#define MM(m, n, AH, AL, BH, BL)                                               \
  do {                                                                         \
    acc[m][n] = __builtin_amdgcn_mfma_f32_32x32x16_f16(AH, BH, acc[m][n], 0,   \
                                                       0, 0);                  \
    acc[m][n] = __builtin_amdgcn_mfma_f32_32x32x16_f16(AH, BL, acc[m][n], 0,   \
                                                       0, 0);                  \
    acc[m][n] = __builtin_amdgcn_mfma_f32_32x32x16_f16(AL, BH, acc[m][n], 0,   \
                                                       0, 0);                  \
  } while (0)

#define TILE(T, STG, WRT)                                                      \
  do {                                                                         \
    char* cbase = smem + ((T) & 3) * 32768;                                    \
    if (WRT) WRITE_A(((T) + 1) & 3); /* publish A(T+1) from held regs */       \
    if (STG) LOAD_A((T) + 2);        /* issue A(T+2), lands during T+1 */      \
    half8 a0h = *(const half8*)(cbase + afr[0]);                               \
    half8 a0l = *(const half8*)(cbase + 8192 + afr[0]);                        \
    half8 a1h = *(const half8*)(cbase + afr[1]);                               \
    half8 a1l = *(const half8*)(cbase + 8192 + afr[1]);                        \
    half8 b0h = *(const half8*)(cbase + 16384 + bfr[0]);                       \
    half8 b0l = *(const half8*)(cbase + 24576 + bfr[0]);                       \
    half8 b1h = *(const half8*)(cbase + 16384 + bfr[1]);                       \
    half8 b1l = *(const half8*)(cbase + 24576 + bfr[1]);                       \
    __builtin_amdgcn_s_barrier();                                              \
    asm volatile("s_waitcnt lgkmcnt(0)" ::: "memory");                         \
    __builtin_amdgcn_sched_barrier(0);                                         \
    __builtin_amdgcn_s_setprio(1);                                             \
    MM(0, 0, a0h, a0l, b0h, b0l);                                              \
    MM(0, 1, a0h, a0l, b1h, b1l);                                              \
    MM(1, 0, a1h, a1l, b0h, b0l);                                              \
    MM(1, 1, a1h, a1l, b1h, b1l);                                              \
    __builtin_amdgcn_s_setprio(0);                                             \
    __builtin_amdgcn_sched_barrier(0);                                         \
    if (STG) GLD_B((T) + 2); /* issue B(T+2), in flight across barriers */     \
    half8 a2h = *(const half8*)(cbase + afr[2]);                               \
    half8 a2l = *(const half8*)(cbase + 8192 + afr[2]);                        \
    half8 a3h = *(const half8*)(cbase + afr[3]);                               \
    half8 a3l = *(const half8*)(cbase + 8192 + afr[3]);                        \
    __builtin_amdgcn_s_barrier();                                              \
    asm volatile("s_waitcnt lgkmcnt(0)" ::: "memory");                         \
    __builtin_amdgcn_sched_barrier(0);                                         \
    __builtin_amdgcn_s_setprio(1);                                             \
    MM(2, 0, a2h, a2l, b0h, b0l);                                              \
    MM(2, 1, a2h, a2l, b1h, b1l);                                              \
    MM(3, 0, a3h, a3l, b0h, b0l);                                              \
    MM(3, 1, a3h, a3l, b1h, b1l);                                              \
    __builtin_amdgcn_s_setprio(0);                                             \
    __builtin_amdgcn_sched_barrier(0);                                         \
    if (STG)                                                                   \
      asm volatile("s_waitcnt vmcnt(4)" ::: "memory"); /* T+1 done; T+2 in */  \
    else                                                                       \
      asm volatile("s_waitcnt vmcnt(0)" ::: "memory");                         \
    __builtin_amdgcn_s_barrier();                                              \
    __builtin_amdgcn_sched_barrier(0);                                         \
  } while (0)

  // ---- Prologue: tiles 0 and 1 staged; av left holding A(1) ----
  LOAD_A(0);
  WRITE_A(0);  // compiler inserts the vmcnt wait for av here
  LOAD_A(1);
  GLD_B(0);
  GLD_B(1);
  asm volatile("s_waitcnt lgkmcnt(0)" ::: "memory");  // publish A(0) writes
  asm volatile("s_waitcnt vmcnt(2)" ::: "memory");    // B(0) resident
  __builtin_amdgcn_s_barrier();
  __builtin_amdgcn_sched_barrier(0);

#pragma unroll 1
  for (int T = 0; T < 126; ++T) {
    TILE(T, 1, 1);
  }
  TILE(126, 0, 1);
  TILE(127, 0, 0);

#undef LOAD_A
#undef WRITE_A
#undef GLD_B
#undef MM
#undef TILE

  // Epilogue: 32x32 C/D layout col=lane&31, row=(j&3)+8*(j>>2)+4*(lane>>5)
#pragma unroll
  for (int m = 0; m < 4; m++) {
#pragma unroll
    for (int n = 0; n < 2; n++) {
      const int c = col0 + wc * 64 + n * 32 + l31;
#pragma unroll
      for (int j = 0; j < 16; j++) {
        const int r = row0 + wr * 128 + m * 32 + (j & 3) + 8 * (j >> 2) + 4 * kg;
        h[(size_t)r * H_DIM + c] = acc[m][n][j];
      }
    }
  }
}

// ---------------------------------------------------------------------------
// Kernel 2: per 8 tokens: +b1, LayerNorm, exact GELU, logits = g @ W2 + b2,
// softmax, top-2 (lower-index tie-break), renorm weights.
// ---------------------------------------------------------------------------
__device__ __forceinline__ float gelu_exact(float v) {
  return 0.5f * v * (1.0f + erff(v * 0.70710678118654752f));
}

__global__ __launch_bounds__(256) void router_kernel(
    const float* __restrict__ hbuf, const float* __restrict__ b1,
    const float* __restrict__ gamma, const float* __restrict__ beta,
    const float* __restrict__ W2, const float* __restrict__ b2,
    float* __restrict__ out) {
  __shared__ float g[8][H_DIM];
  __shared__ float w2s[128][E_DIM];
  __shared__ float lg[8][E_DIM];

  const int t = threadIdx.x;
  const int tok0 = blockIdx.x * 8;

  const int tk = t >> 5;
  const int l32 = t & 31;
  float vals[32];
  {
    const float* hr = hbuf + (size_t)(tok0 + tk) * H_DIM;
    float s = 0.f, s2 = 0.f;
#pragma unroll
    for (int q = 0; q < 8; q++) {
      const int j = q * 128 + l32 * 4;
      float4 v = *(const float4*)(hr + j);
      float4 bb = *(const float4*)(b1 + j);
      v.x += bb.x; v.y += bb.y; v.z += bb.z; v.w += bb.w;
      vals[q * 4 + 0] = v.x; vals[q * 4 + 1] = v.y;
      vals[q * 4 + 2] = v.z; vals[q * 4 + 3] = v.w;
      s += v.x + v.y + v.z + v.w;
      s2 += v.x * v.x + v.y * v.y + v.z * v.z + v.w * v.w;
    }
#pragma unroll
    for (int off = 16; off; off >>= 1) {
      s += __shfl_xor(s, off, 32);
      s2 += __shfl_xor(s2, off, 32);
    }
    const float mean = s * (1.f / 1024.f);
    const float var = s2 * (1.f / 1024.f) - mean * mean;
    const float rstd = rsqrtf(var + 1e-5f);
#pragma unroll
    for (int q = 0; q < 8; q++) {
      const int j = q * 128 + l32 * 4;
      float4 gm = *(const float4*)(gamma + j);
      float4 bt = *(const float4*)(beta + j);
      float4 o;
      o.x = gelu_exact((vals[q * 4 + 0] - mean) * rstd * gm.x + bt.x);
      o.y = gelu_exact((vals[q * 4 + 1] - mean) * rstd * gm.y + bt.y);
      o.z = gelu_exact((vals[q * 4 + 2] - mean) * rstd * gm.z + bt.z);
      o.w = gelu_exact((vals[q * 4 + 3] - mean) * rstd * gm.w + bt.w);
      *(float4*)&g[tk][j] = o;
    }
  }

  {
    float* lgf = &lg[0][0];
    lgf[t] = b2[t & 63];
    lgf[t + 256] = b2[t & 63];
  }

  const int seg = t >> 6;
  const int cell = t & 63;
  const int tp = cell >> 4;
  const int e0 = (cell & 15) * 4;

  float acc0[4] = {0.f, 0.f, 0.f, 0.f};
  float acc1[4] = {0.f, 0.f, 0.f, 0.f};

  for (int c = 0; c < 8; c++) {
    __syncthreads();
#pragma unroll
    for (int q = 0; q < 8; q++) {
      const int idx = q * 1024 + t * 4;
      *(float4*)(&w2s[0][0] + idx) = *(const float4*)(W2 + c * 8192 + idx);
    }
    __syncthreads();
#pragma unroll
    for (int q = 0; q < 8; q++) {
      const int i = seg * 32 + q * 4;
      float4 g0 = *(const float4*)&g[2 * tp][c * 128 + i];
      float4 g1 = *(const float4*)&g[2 * tp + 1][c * 128 + i];
      float4 w0 = *(const float4*)&w2s[i + 0][e0];
      float4 w1 = *(const float4*)&w2s[i + 1][e0];
      float4 w2v = *(const float4*)&w2s[i + 2][e0];
      float4 w3 = *(const float4*)&w2s[i + 3][e0];
      acc0[0] = fmaf(g0.x, w0.x, acc0[0]); acc0[1] = fmaf(g0.x, w0.y, acc0[1]);
      acc0[2] = fmaf(g0.x, w0.z, acc0[2]); acc0[3] = fmaf(g0.x, w0.w, acc0[3]);
      acc0[0] = fmaf(g0.y, w1.x, acc0[0]); acc0[1] = fmaf(g0.y, w1.y, acc0[1]);
      acc0[2] = fmaf(g0.y, w1.z, acc0[2]); acc0[3] = fmaf(g0.y, w1.w, acc0[3]);
      acc0[0] = fmaf(g0.z, w2v.x, acc0[0]); acc0[1] = fmaf(g0.z, w2v.y, acc0[1]);
      acc0[2] = fmaf(g0.z, w2v.z, acc0[2]); acc0[3] = fmaf(g0.z, w2v.w, acc0[3]);
      acc0[0] = fmaf(g0.w, w3.x, acc0[0]); acc0[1] = fmaf(g0.w, w3.y, acc0[1]);
      acc0[2] = fmaf(g0.w, w3.z, acc0[2]); acc0[3] = fmaf(g0.w, w3.w, acc0[3]);
      acc1[0] = fmaf(g1.x, w0.x, acc1[0]); acc1[1] = fmaf(g1.x, w0.y, acc1[1]);
      acc1[2] = fmaf(g1.x, w0.z, acc1[2]); acc1[3] = fmaf(g1.x, w0.w, acc1[3]);
      acc1[0] = fmaf(g1.y, w1.x, acc1[0]); acc1[1] = fmaf(g1.y, w1.y, acc1[1]);
      acc1[2] = fmaf(g1.y, w1.z, acc1[2]); acc1[3] = fmaf(g1.y, w1.w, acc1[3]);
      acc1[0] = fmaf(g1.z, w2v.x, acc1[0]); acc1[1] = fmaf(g1.z, w2v.y, acc1[1]);
      acc1[2] = fmaf(g1.z, w2v.z, acc1[2]); acc1[3] = fmaf(g1.z, w2v.w, acc1[3]);
      acc1[0] = fmaf(g1.w, w3.x, acc1[0]); acc1[1] = fmaf(g1.w, w3.y, acc1[1]);
      acc1[2] = fmaf(g1.w, w3.z, acc1[2]); acc1[3] = fmaf(g1.w, w3.w, acc1[3]);
    }
  }
#pragma unroll
  for (int j = 0; j < 4; j++) {
    atomicAdd(&lg[2 * tp][e0 + j], acc0[j]);
    atomicAdd(&lg[2 * tp + 1][e0 + j], acc1[j]);
  }
  __syncthreads();

  float* out_idx = out;
  float* out_w = out + 32768;
  float* out_logits = out + 65536;

  const int wv = t >> 6;
  const int lane = t & 63;
#pragma unroll
  for (int tt = 0; tt < 2; tt++) {
    const int tok = wv * 2 + tt;
    const int n = tok0 + tok;
    const float L = lg[tok][lane];
    float m = L;
#pragma unroll
    for (int off = 32; off; off >>= 1) m = fmaxf(m, __shfl_xor(m, off));
    const float ex = expf(L - m);
    float sum = ex;
#pragma unroll
    for (int off = 32; off; off >>= 1) sum += __shfl_xor(sum, off);
    const float p = ex / sum;

    float v1 = p; int i1 = lane;
#pragma unroll
    for (int off = 32; off; off >>= 1) {
      float ov = __shfl_xor(v1, off);
      int oi = __shfl_xor(i1, off);
      if (ov > v1 || (ov == v1 && oi < i1)) { v1 = ov; i1 = oi; }
    }
    float v2 = (lane == i1) ? -1.f : p; int i2 = lane;
#pragma unroll
    for (int off = 32; off; off >>= 1) {
      float ov = __shfl_xor(v2, off);
      int oi = __shfl_xor(i2, off);
      if (ov > v2 || (ov == v2 && oi < i2)) { v2 = ov; i2 = oi; }
    }

    out_logits[(size_t)n * 64 + lane] = L;
    if (lane == 0) {
      const float dn = v1 + v2 + 1e-9f;
      out_idx[n * 2 + 0] = (float)i1;
      out_idx[n * 2 + 1] = (float)i2;
      out_w[n * 2 + 0] = v1 / dn;
      out_w[n * 2 + 1] = v2 / dn;
    }
  }
}

extern "C" void kernel_launch(void* const* d_in, const int* in_sizes, int n_in,
                              void* d_out, int out_size, void* d_ws, size_t ws_size,
                              hipStream_t stream) {
  const float* x = (const float*)d_in[0];
  const float* W1 = (const float*)d_in[1];
  const float* b1 = (const float*)d_in[2];
  const float* gamma = (const float*)d_in[3];
  const float* beta = (const float*)d_in[4];
  const float* W2 = (const float*)d_in[5];
  const float* b2 = (const float*)d_in[6];
  float* out = (float*)d_out;

  char* ws = (char*)d_ws;
  _Float16* whT = (_Float16*)ws;                 // 4 MiB
  _Float16* wlT = (_Float16*)(ws + 4194304);     // 4 MiB
  float* hbuf = (float*)(ws + 8388608);          // 64 MiB (total 72 MiB)

  (void)hipFuncSetAttribute((const void*)gemm1_mfma_kernel,
                            hipFuncAttributeMaxDynamicSharedMemorySize,
                            131072);

  splitT_w1_kernel<<<dim3(D_DIM / 64, H_DIM / 64), 256, 0, stream>>>(W1, whT, wlT);

  gemm1_mfma_kernel<<<256, 512, 131072, stream>>>(x, whT, wlT, hbuf);

  router_kernel<<<N_TOK / 8, 256, 0, stream>>>(hbuf, b1, gamma, beta, W2, b2, out);
}